// Round 15
// baseline (151.162 us; speedup 1.0000x reference)
//
#include <hip/hip_runtime.h>
#include <hip/hip_bf16.h>
#include <cstdint>
#include <cstddef>

#define BB 2
#define NN 2048
#define CC 1024
#define HH 16
#define DD 64
#define MM (BB*NN)   /* 4096 rows of x */

typedef __attribute__((ext_vector_type(8))) _Float16 half8;
typedef __attribute__((ext_vector_type(4))) _Float16 half4;
typedef __attribute__((ext_vector_type(4))) float f32x4;

__device__ __forceinline__ float exp2_fast(float x) {
    float r; asm("v_exp_f32 %0, %1" : "=v"(r) : "v"(x)); return r;
}

// global -> LDS direct copy, 16B per lane. LDS dest must be uniform base + lane*16.
__device__ __forceinline__ void gl_lds16(const void* g, void* l) {
    __builtin_amdgcn_global_load_lds(
        (const __attribute__((address_space(1))) unsigned int*)g,
        (__attribute__((address_space(3))) unsigned int*)l, 16, 0, 0);
}

// ---------------------------------------------------------------------------
// Fused fp32 -> fp16 convert: x (1M float4) then Wq,Wk,Wv,Wp (256K float4 each)
// ---------------------------------------------------------------------------
__global__ __launch_bounds__(256) void cvtAll(
    const float* __restrict__ x, const float* __restrict__ wq,
    const float* __restrict__ wk, const float* __restrict__ wv,
    const float* __restrict__ wp, _Float16* __restrict__ X16,
    _Float16* __restrict__ W16) {
    const int NX4 = MM * CC / 4;     // 1048576
    const int NW4 = CC * CC / 4;     // 262144 = 2^18
    int i = blockIdx.x * 256 + threadIdx.x;
    const float4* src;
    half4* dst;
    if (i < NX4) {
        src = (const float4*)x + i;
        dst = (half4*)X16 + i;
    } else {
        int j = i - NX4;
        int s = j >> 18, off = j & (NW4 - 1);
        const float* wsel = (s == 0) ? wq : (s == 1) ? wk : (s == 2) ? wv : wp;
        src = (const float4*)wsel + off;
        dst = (half4*)(W16 + (size_t)s * CC * CC) + off;
    }
    float4 v = *src;
    half4 h = { (_Float16)v.x, (_Float16)v.y, (_Float16)v.z, (_Float16)v.w };
    *dst = h;
}

// ---------------------------------------------------------------------------
// Fused QKV: C = X * Wqkv^T. 128x128 tile, BK=64, 4 waves. XCD-bijective
// bm swizzle. Epilogue scatter: Q (*qscale) / K / V-transposed.
// ---------------------------------------------------------------------------
__global__ __launch_bounds__(256) void gemmQKV(
    const _Float16* __restrict__ A, const _Float16* __restrict__ B,
    _Float16* __restrict__ QH, _Float16* __restrict__ KH,
    _Float16* __restrict__ VT, float qscale) {
    __shared__ _Float16 sA[128 * 64];
    __shared__ _Float16 sB[128 * 64];
    const int K = CC;

    const int t = threadIdx.x;
    const int id = blockIdx.y * gridDim.x + blockIdx.x;
    const int xcd = id & 7, kk = id >> 3;
    const int bm = xcd * 4 + (kk & 3);   // 0..31
    const int bn = kk >> 2;              // 0..23
    const int w = t >> 6, lane = t & 63;
    const int wr = (w >> 1) * 64, wc = (w & 1) * 64;
    const int lr = lane & 15, lg = lane >> 4;

    f32x4 acc[4][4];
#pragma unroll
    for (int a = 0; a < 4; ++a)
#pragma unroll
        for (int b2 = 0; b2 < 4; ++b2)
#pragma unroll
            for (int e = 0; e < 4; ++e) acc[a][b2][e] = 0.f;

    for (int kt = 0; kt < K; kt += 64) {
#pragma unroll
        for (int p = 0; p < 4; ++p) {
            int u = p * 256 + t;
            int rowu = u >> 3, su = (u & 7) ^ (rowu & 7);
            gl_lds16(A + (size_t)(bm * 128 + rowu) * K + kt + su * 8, sA + u * 8);
            gl_lds16(B + (size_t)(bn * 128 + rowu) * K + kt + su * 8, sB + u * 8);
        }
        __syncthreads();

#pragma unroll
        for (int c = 0; c < 2; ++c) {
            half8 af[4], bf[4];
#pragma unroll
            for (int f = 0; f < 4; ++f) {
                int ra = wr + f * 16 + lr;
                af[f] = *(const half8*)((const char*)sA + ((ra * 128 + c * 64 + lg * 16) ^ ((ra & 7) << 4)));
                int rb = wc + f * 16 + lr;
                bf[f] = *(const half8*)((const char*)sB + ((rb * 128 + c * 64 + lg * 16) ^ ((rb & 7) << 4)));
            }
#pragma unroll
            for (int fi = 0; fi < 4; ++fi)
#pragma unroll
                for (int fj = 0; fj < 4; ++fj)
                    acc[fi][fj] = __builtin_amdgcn_mfma_f32_16x16x32_f16(af[fi], bf[fj], acc[fi][fj], 0, 0, 0);
        }
        __syncthreads();
    }

    // C/D layout: col = lane&15, row = (lane>>4)*4 + reg
#pragma unroll
    for (int fi = 0; fi < 4; ++fi)
#pragma unroll
        for (int fj = 0; fj < 4; ++fj) {
            int col = bn * 128 + wc + fj * 16 + lr;
            int sel = col >> 10, c10 = col & 1023;
            int h2 = c10 >> 6, d2 = c10 & 63;
            int rowb = bm * 128 + wr + fi * 16 + lg * 4;
            int b2 = rowb >> 11, n2 = rowb & (NN - 1);
            if (sel == 0) {
#pragma unroll
                for (int e = 0; e < 4; ++e)
                    QH[((size_t)(b2 * HH + h2) * NN + n2 + e) * DD + d2] =
                        (_Float16)(acc[fi][fj][e] * qscale);
            } else if (sel == 1) {
#pragma unroll
                for (int e = 0; e < 4; ++e)
                    KH[((size_t)(b2 * HH + h2) * NN + n2 + e) * DD + d2] =
                        (_Float16)acc[fi][fj][e];
            } else {
                half4 pk = { (_Float16)acc[fi][fj][0], (_Float16)acc[fi][fj][1],
                             (_Float16)acc[fi][fj][2], (_Float16)acc[fi][fj][3] };
                *(half4*)(VT + ((size_t)(b2 * HH + h2) * DD + d2) * NN + n2) = pk;
            }
        }
}

// ---------------------------------------------------------------------------
// PROJ: C = A * B^T + bias, fp32 out. 128x64 tile, BK=64, XCD bm swizzle.
// ---------------------------------------------------------------------------
__global__ __launch_bounds__(256) void gemmPROJ(
    const _Float16* __restrict__ A, const _Float16* __restrict__ B,
    const float* __restrict__ bias, float* __restrict__ Cout) {
    __shared__ _Float16 sA[128 * 64];
    __shared__ _Float16 sB[64 * 64];
    const int K = CC, N = CC;

    const int t = threadIdx.x;
    const int id = blockIdx.y * gridDim.x + blockIdx.x;
    const int xcd = id & 7, kk = id >> 3;
    const int bm = xcd * 4 + (kk & 3);   // 0..31
    const int bn = kk >> 2;              // 0..15
    const int w = t >> 6, lane = t & 63;
    const int wr = (w >> 1) * 64, wc = (w & 1) * 32;
    const int lr = lane & 15, lg = lane >> 4;

    f32x4 acc[4][2];
#pragma unroll
    for (int a = 0; a < 4; ++a)
#pragma unroll
        for (int b2 = 0; b2 < 2; ++b2)
#pragma unroll
            for (int e = 0; e < 4; ++e) acc[a][b2][e] = 0.f;

    for (int kt = 0; kt < K; kt += 64) {
#pragma unroll
        for (int p = 0; p < 4; ++p) {     // A: 1024 16B-units
            int u = p * 256 + t;
            int rowu = u >> 3, su = (u & 7) ^ (rowu & 7);
            gl_lds16(A + (size_t)(bm * 128 + rowu) * K + kt + su * 8, sA + u * 8);
        }
#pragma unroll
        for (int p = 0; p < 2; ++p) {     // B: 512 16B-units
            int u = p * 256 + t;
            int rowu = u >> 3, su = (u & 7) ^ (rowu & 7);
            gl_lds16(B + (size_t)(bn * 64 + rowu) * K + kt + su * 8, sB + u * 8);
        }
        __syncthreads();

#pragma unroll
        for (int c = 0; c < 2; ++c) {
            half8 af[4], bf[2];
#pragma unroll
            for (int f = 0; f < 4; ++f) {
                int ra = wr + f * 16 + lr;
                af[f] = *(const half8*)((const char*)sA + ((ra * 128 + c * 64 + lg * 16) ^ ((ra & 7) << 4)));
            }
#pragma unroll
            for (int f = 0; f < 2; ++f) {
                int rb = wc + f * 16 + lr;
                bf[f] = *(const half8*)((const char*)sB + ((rb * 128 + c * 64 + lg * 16) ^ ((rb & 7) << 4)));
            }
#pragma unroll
            for (int fi = 0; fi < 4; ++fi)
#pragma unroll
                for (int fj = 0; fj < 2; ++fj)
                    acc[fi][fj] = __builtin_amdgcn_mfma_f32_16x16x32_f16(af[fi], bf[fj], acc[fi][fj], 0, 0, 0);
        }
        __syncthreads();
    }

#pragma unroll
    for (int fi = 0; fi < 4; ++fi)
#pragma unroll
        for (int fj = 0; fj < 2; ++fj)
#pragma unroll
            for (int e = 0; e < 4; ++e) {
                int row = bm * 128 + wr + fi * 16 + lg * 4 + e;
                int col = bn * 64 + wc + fj * 16 + lr;
                Cout[(size_t)row * N + col] = acc[fi][fj][e] + bias[col];
            }
}

// ---------------------------------------------------------------------------
// Producer-consumer fp16 MFMA flash attention with ALiBi (r10/r12 structure)
// + amdgpu_waves_per_eu(2,4): tells the allocator occupancy is capped at
// 4 waves/EU (which LDS=67KB already enforces at 2 blocks/CU) so it may use
// up to 128 VGPR instead of spilling at the 8-wave/EU heuristic's 64 (the
// r11 failure mechanism). With the budget unlocked, the r11 VALU diet:
//  - ALiBi C-init via MFMA C-operand (cfull, loop-invariant, zero init VALU)
//  - msh-fold (branch-free tile-local logits)
//  - l via ones-row MFMA in consumers (producers drop sum tree + handoff;
//    also rebalances the producer-heavy barrier gang)
// ---------------------------------------------------------------------------
__global__ __launch_bounds__(512) __attribute__((amdgpu_waves_per_eu(2, 4)))
void attnPC(
    const _Float16* __restrict__ Qh, const _Float16* __restrict__ Kh,
    const _Float16* __restrict__ Vt, _Float16* __restrict__ AO) {
    __shared__ _Float16 sK[2][64 * 64];        // 16 KB
    __shared__ _Float16 sV[2][64 * 64];        // 16 KB
    __shared__ _Float16 sP[2][4][32 * 64];     // 32 KB, per-producer, XOR-swz
    __shared__ float sAl[2][4][32];            // 1 KB  alpha per q

    const int t = threadIdx.x, w = t >> 6, lane = t & 63;
    const int lr = lane & 15, lg = lane >> 4;
    const int bh = blockIdx.x, qb = blockIdx.y;   // id%8 = bh%8 -> K/V L2-pinned
    const int b = bh >> 4, h = bh & 15;
    const int i0 = qb * 128;
    const size_t baseND = (size_t)bh * NN * DD;
    const size_t baseDN = (size_t)bh * DD * NN;
    const bool isProd = (w < 4);
    const int pw = w & 3;

    const float slope2 = exp2f(-0.5f * (float)(h + 1)) * 1.44269504f;
    const float s64v = slope2 * 64.f;

    // 512-thread staging: one 16B unit per thread per call
    auto stageK = [&](int buf, int jt) {
        int rowu = t >> 3, su = (t & 7) ^ (rowu & 7);
        gl_lds16(Kh + baseND + (size_t)(jt * 64 + rowu) * DD + su * 8, &sK[buf][t * 8]);
    };
    auto stageV = [&](int buf, int jt) {
        int rowu = t >> 3, su = (t & 7) ^ (rowu & 7);
        gl_lds16(Vt + baseDN + (size_t)rowu * NN + jt * 64 + su * 8, &sV[buf][t * 8]);
    };

    // ---- producer state ----
    half8 qf[2][2];
    f32x4 cfull[4];              // slope2*(ct*16+lg*4+e), loop-invariant C-in
    float m_run[2], tbp = 0.f;
    // ---- consumer state ----
    f32x4 accO[2][4];
    f32x4 accL[2];               // ones-row P sums (all 4 elems equal)

    if (isProd) {
#pragma unroll
        for (int u = 0; u < 2; ++u) {
            const size_t qoff = baseND + (size_t)(i0 + pw * 32 + u * 16 + lr) * DD;
            qf[u][0] = *(const half8*)(Qh + qoff + 0 * 32 + lg * 8);
            qf[u][1] = *(const half8*)(Qh + qoff + 1 * 32 + lg * 8);
        }
#pragma unroll
        for (int ct = 0; ct < 4; ++ct)
#pragma unroll
            for (int e = 0; e < 4; ++e)
                cfull[ct][e] = slope2 * (float)(ct * 16 + lg * 4 + e);
        m_run[0] = m_run[1] = -INFINITY;
    } else {
#pragma unroll
        for (int u = 0; u < 2; ++u) {
            accL[u][0] = accL[u][1] = accL[u][2] = accL[u][3] = 0.f;
#pragma unroll
            for (int c2 = 0; c2 < 4; ++c2)
                accO[u][c2][0] = accO[u][c2][1] = accO[u][c2][2] = accO[u][c2][3] = 0.f;
        }
    }

    // producer step: QK^T + softmax + publish P/alpha into buffers [pb]
    auto prodStep = [&](int pb, int kb) {
        f32x4 s0[4], s1[4];
        __builtin_amdgcn_s_setprio(1);
#pragma unroll
        for (int ct = 0; ct < 4; ++ct) {
            int row = ct * 16 + lr;
            half8 kf0 = *(const half8*)((const char*)&sK[kb][0] +
                ((row * 128 + 0 * 64 + lg * 16) ^ ((row & 7) << 4)));
            s0[ct] = __builtin_amdgcn_mfma_f32_16x16x32_f16(kf0, qf[0][0], cfull[ct], 0, 0, 0);
            s1[ct] = __builtin_amdgcn_mfma_f32_16x16x32_f16(kf0, qf[1][0], cfull[ct], 0, 0, 0);
            half8 kf1 = *(const half8*)((const char*)&sK[kb][0] +
                ((row * 128 + 1 * 64 + lg * 16) ^ ((row & 7) << 4)));
            s0[ct] = __builtin_amdgcn_mfma_f32_16x16x32_f16(kf1, qf[0][1], s0[ct], 0, 0, 0);
            s1[ct] = __builtin_amdgcn_mfma_f32_16x16x32_f16(kf1, qf[1][1], s1[ct], 0, 0, 0);
        }
        __builtin_amdgcn_s_setprio(0);
#pragma unroll
        for (int u = 0; u < 2; ++u) {
            f32x4* s = u ? s1 : s0;
            float x0 = fmaxf(fmaxf(s[0][0], s[0][1]), fmaxf(s[0][2], s[0][3]));
            float x1 = fmaxf(fmaxf(s[1][0], s[1][1]), fmaxf(s[1][2], s[1][3]));
            float x2 = fmaxf(fmaxf(s[2][0], s[2][1]), fmaxf(s[2][2], s[2][3]));
            float x3 = fmaxf(fmaxf(s[3][0], s[3][1]), fmaxf(s[3][2], s[3][3]));
            float mx = fmaxf(fmaxf(x0, x1), fmaxf(x2, x3));
            mx = fmaxf(mx, __shfl_xor(mx, 16, 64));
            mx = fmaxf(mx, __shfl_xor(mx, 32, 64));
            float mxt = mx + tbp;
            float mnew = fmaxf(m_run[u], mxt);
            float al = exp2_fast(m_run[u] - mnew);   // first tile: exp2(-inf)=0
            float msh = mnew - tbp;
            m_run[u] = mnew;
            int row = u * 16 + lr;
#pragma unroll
            for (int ct = 0; ct < 4; ++ct) {
                float p0 = exp2_fast(s[ct][0] - msh);
                float p1 = exp2_fast(s[ct][1] - msh);
                float p2 = exp2_fast(s[ct][2] - msh);
                float p3 = exp2_fast(s[ct][3] - msh);
                unsigned plo = __builtin_bit_cast(unsigned, __builtin_amdgcn_cvt_pkrtz(p0, p1));
                unsigned phi = __builtin_bit_cast(unsigned, __builtin_amdgcn_cvt_pkrtz(p2, p3));
                uint2 pk = { plo, phi };
                *(uint2*)((char*)sP[pb][pw] + ((row * 128 + ct * 32 + lg * 8) ^ ((lr & 7) << 4))) = pk;
            }
            if (lg == 0) sAl[pb][pw][row] = al;
        }
        tbp += s64v;
    };

    // consumer step: rescale + PV (+ ones-row l) for one tile
    auto consStep = [&](int vb) {
        float al0 = sAl[vb][pw][lr];
        float al1 = sAl[vb][pw][16 + lr];
#pragma unroll
        for (int c2 = 0; c2 < 4; ++c2)
#pragma unroll
            for (int e = 0; e < 4; ++e) { accO[0][c2][e] *= al0; accO[1][c2][e] *= al1; }
#pragma unroll
        for (int e = 0; e < 4; ++e) { accL[0][e] *= al0; accL[1][e] *= al1; }
        half8 pb0[2], pb1[2];
#pragma unroll
        for (int c = 0; c < 2; ++c) {
            pb0[c] = *(const half8*)((const char*)sP[vb][pw] +
                ((lr * 128 + c * 64 + lg * 16) ^ ((lr & 7) << 4)));
            pb1[c] = *(const half8*)((const char*)sP[vb][pw] +
                (((16 + lr) * 128 + c * 64 + lg * 16) ^ ((lr & 7) << 4)));
        }
        const half8 ones = { (_Float16)1.f, (_Float16)1.f, (_Float16)1.f, (_Float16)1.f,
                             (_Float16)1.f, (_Float16)1.f, (_Float16)1.f, (_Float16)1.f };
        __builtin_amdgcn_s_setprio(1);
#pragma unroll
        for (int ctd = 0; ctd < 4; ++ctd)
#pragma unroll
            for (int c = 0; c < 2; ++c) {
                int row = ctd * 16 + lr;
                half8 vf = *(const half8*)((const char*)&sV[vb][0] +
                    ((row * 128 + c * 64 + lg * 16) ^ ((row & 7) << 4)));
                accO[0][ctd] = __builtin_amdgcn_mfma_f32_16x16x32_f16(vf, pb0[c], accO[0][ctd], 0, 0, 0);
                accO[1][ctd] = __builtin_amdgcn_mfma_f32_16x16x32_f16(vf, pb1[c], accO[1][ctd], 0, 0, 0);
            }
#pragma unroll
        for (int c = 0; c < 2; ++c) {
            accL[0] = __builtin_amdgcn_mfma_f32_16x16x32_f16(ones, pb0[c], accL[0], 0, 0, 0);
            accL[1] = __builtin_amdgcn_mfma_f32_16x16x32_f16(ones, pb1[c], accL[1], 0, 0, 0);
        }
        __builtin_amdgcn_s_setprio(0);
    };

    // ---- prologue ----
    stageK(0, 0); stageK(1, 1); stageV(0, 0);
    __syncthreads();                 // K0,K1,V0 ready
    if (isProd) prodStep(0, 0);      // tile 0 -> P[0], alpha[0]
    __syncthreads();                 // P[0] ready

    // ---- main loop: one barrier per tile ----
    for (int j = 0; j < 32; ++j) {
        if (j + 2 < 32) stageK(j & 1, j + 2);          // overwrites K(j): dead
        if (j + 1 < 32) stageV((j + 1) & 1, j + 1);    // overwrites V(j-1): dead
        if (isProd) {
            if (j + 1 < 32) prodStep((j + 1) & 1, (j + 1) & 1);
        } else {
            consStep(j & 1);
        }
        __syncthreads();
    }

    // ---- epilogue: consumers own l (= accL) and write AO ----
    if (!isProd) {
#pragma unroll
        for (int u = 0; u < 2; ++u) {
            float rl = 1.0f / accL[u][0];
            const size_t obase = ((size_t)b * NN + i0 + pw * 32 + u * 16 + lr) * CC + h * DD;
#pragma unroll
            for (int ctd = 0; ctd < 4; ++ctd) {
                half4 ov = { (_Float16)(accO[u][ctd][0] * rl), (_Float16)(accO[u][ctd][1] * rl),
                             (_Float16)(accO[u][ctd][2] * rl), (_Float16)(accO[u][ctd][3] * rl) };
                *(half4*)(AO + obase + ctd * 16 + lg * 4) = ov;
            }
        }
    }
}

// ---------------------------------------------------------------------------
extern "C" void kernel_launch(void* const* d_in, const int* in_sizes, int n_in,
                              void* d_out, int out_size, void* d_ws, size_t ws_size,
                              hipStream_t stream) {
    const float* x  = (const float*)d_in[0];
    const float* Wq = (const float*)d_in[1];
    const float* Wk = (const float*)d_in[2];
    const float* Wv = (const float*)d_in[3];
    const float* Wp = (const float*)d_in[4];
    const float* bp = (const float*)d_in[5];
    float* out = (float*)d_out;

    char* ws = (char*)d_ws;
    const size_t MB = 1024 * 1024;
    _Float16* X16 = (_Float16*)(ws + 0 * MB);    // 8 MB
    _Float16* W16 = (_Float16*)(ws + 8 * MB);    // 4 x 2 MB (Wq,Wk,Wv,Wp)
    _Float16* QH  = (_Float16*)(ws + 16 * MB);   // 8 MB  [B,H,N,D], q*8*log2e
    _Float16* KH  = (_Float16*)(ws + 24 * MB);   // 8 MB  [B,H,N,D]
    _Float16* VT  = (_Float16*)(ws + 32 * MB);   // 8 MB  [B,H,D,N]
    _Float16* AO  = (_Float16*)(ws + 40 * MB);   // 8 MB  [B,N,C]
    _Float16* WP16 = W16 + 3 * 1024 * 1024;

    cvtAll<<<8192, 256, 0, stream>>>(x, Wq, Wk, Wv, Wp, X16, W16);

    const float QSCALE = 8.0f * 1.44269504f;   // fold 1/SCALE and log2(e)
    gemmQKV<<<dim3(3 * CC / 128, MM / 128), 256, 0, stream>>>(X16, W16, QH, KH, VT, QSCALE);

    // grid = (bh, qb): id%8 = bh%8 -> all q-blocks of a head share an XCD
    attnPC<<<dim3(BB * HH, NN / 128), 512, 0, stream>>>(QH, KH, VT, AO);

    gemmPROJ<<<dim3(CC / 64, MM / 128), 256, 0, stream>>>(AO, WP16, bp, out);
}

// Round 16
// 137.439 us; speedup vs baseline: 1.0998x; 1.0998x over previous
//
#include <hip/hip_runtime.h>
#include <hip/hip_bf16.h>
#include <cstdint>
#include <cstddef>

#define BB 2
#define NN 2048
#define CC 1024
#define HH 16
#define DD 64
#define MM (BB*NN)   /* 4096 rows of x */

typedef __attribute__((ext_vector_type(8))) _Float16 half8;
typedef __attribute__((ext_vector_type(4))) _Float16 half4;
typedef __attribute__((ext_vector_type(4))) float f32x4;

__device__ __forceinline__ float exp2_fast(float x) {
    float r; asm("v_exp_f32 %0, %1" : "=v"(r) : "v"(x)); return r;
}

// global -> LDS direct copy, 16B per lane. LDS dest must be uniform base + lane*16.
__device__ __forceinline__ void gl_lds16(const void* g, void* l) {
    __builtin_amdgcn_global_load_lds(
        (const __attribute__((address_space(1))) unsigned int*)g,
        (__attribute__((address_space(3))) unsigned int*)l, 16, 0, 0);
}

// ---------------------------------------------------------------------------
// Fused fp32 -> fp16 convert: x (1M float4) then Wq,Wk,Wv,Wp (256K float4 each)
// ---------------------------------------------------------------------------
__global__ __launch_bounds__(256) void cvtAll(
    const float* __restrict__ x, const float* __restrict__ wq,
    const float* __restrict__ wk, const float* __restrict__ wv,
    const float* __restrict__ wp, _Float16* __restrict__ X16,
    _Float16* __restrict__ W16) {
    const int NX4 = MM * CC / 4;     // 1048576
    const int NW4 = CC * CC / 4;     // 262144 = 2^18
    int i = blockIdx.x * 256 + threadIdx.x;
    const float4* src;
    half4* dst;
    if (i < NX4) {
        src = (const float4*)x + i;
        dst = (half4*)X16 + i;
    } else {
        int j = i - NX4;
        int s = j >> 18, off = j & (NW4 - 1);
        const float* wsel = (s == 0) ? wq : (s == 1) ? wk : (s == 2) ? wv : wp;
        src = (const float4*)wsel + off;
        dst = (half4*)(W16 + (size_t)s * CC * CC) + off;
    }
    float4 v = *src;
    half4 h = { (_Float16)v.x, (_Float16)v.y, (_Float16)v.z, (_Float16)v.w };
    *dst = h;
}

// ---------------------------------------------------------------------------
// Fused QKV: C = X * Wqkv^T. 128x128 tile, BK=64, 4 waves. XCD-bijective
// bm swizzle. Epilogue scatter: Q (*qscale) / K / V-transposed.
// ---------------------------------------------------------------------------
__global__ __launch_bounds__(256) void gemmQKV(
    const _Float16* __restrict__ A, const _Float16* __restrict__ B,
    _Float16* __restrict__ QH, _Float16* __restrict__ KH,
    _Float16* __restrict__ VT, float qscale) {
    __shared__ _Float16 sA[128 * 64];
    __shared__ _Float16 sB[128 * 64];
    const int K = CC;

    const int t = threadIdx.x;
    const int id = blockIdx.y * gridDim.x + blockIdx.x;
    const int xcd = id & 7, kk = id >> 3;
    const int bm = xcd * 4 + (kk & 3);   // 0..31
    const int bn = kk >> 2;              // 0..23
    const int w = t >> 6, lane = t & 63;
    const int wr = (w >> 1) * 64, wc = (w & 1) * 64;
    const int lr = lane & 15, lg = lane >> 4;

    f32x4 acc[4][4];
#pragma unroll
    for (int a = 0; a < 4; ++a)
#pragma unroll
        for (int b2 = 0; b2 < 4; ++b2)
#pragma unroll
            for (int e = 0; e < 4; ++e) acc[a][b2][e] = 0.f;

    for (int kt = 0; kt < K; kt += 64) {
#pragma unroll
        for (int p = 0; p < 4; ++p) {
            int u = p * 256 + t;
            int rowu = u >> 3, su = (u & 7) ^ (rowu & 7);
            gl_lds16(A + (size_t)(bm * 128 + rowu) * K + kt + su * 8, sA + u * 8);
            gl_lds16(B + (size_t)(bn * 128 + rowu) * K + kt + su * 8, sB + u * 8);
        }
        __syncthreads();

#pragma unroll
        for (int c = 0; c < 2; ++c) {
            half8 af[4], bf[4];
#pragma unroll
            for (int f = 0; f < 4; ++f) {
                int ra = wr + f * 16 + lr;
                af[f] = *(const half8*)((const char*)sA + ((ra * 128 + c * 64 + lg * 16) ^ ((ra & 7) << 4)));
                int rb = wc + f * 16 + lr;
                bf[f] = *(const half8*)((const char*)sB + ((rb * 128 + c * 64 + lg * 16) ^ ((rb & 7) << 4)));
            }
#pragma unroll
            for (int fi = 0; fi < 4; ++fi)
#pragma unroll
                for (int fj = 0; fj < 4; ++fj)
                    acc[fi][fj] = __builtin_amdgcn_mfma_f32_16x16x32_f16(af[fi], bf[fj], acc[fi][fj], 0, 0, 0);
        }
        __syncthreads();
    }

    // C/D layout: col = lane&15, row = (lane>>4)*4 + reg
#pragma unroll
    for (int fi = 0; fi < 4; ++fi)
#pragma unroll
        for (int fj = 0; fj < 4; ++fj) {
            int col = bn * 128 + wc + fj * 16 + lr;
            int sel = col >> 10, c10 = col & 1023;
            int h2 = c10 >> 6, d2 = c10 & 63;
            int rowb = bm * 128 + wr + fi * 16 + lg * 4;
            int b2 = rowb >> 11, n2 = rowb & (NN - 1);
            if (sel == 0) {
#pragma unroll
                for (int e = 0; e < 4; ++e)
                    QH[((size_t)(b2 * HH + h2) * NN + n2 + e) * DD + d2] =
                        (_Float16)(acc[fi][fj][e] * qscale);
            } else if (sel == 1) {
#pragma unroll
                for (int e = 0; e < 4; ++e)
                    KH[((size_t)(b2 * HH + h2) * NN + n2 + e) * DD + d2] =
                        (_Float16)acc[fi][fj][e];
            } else {
                half4 pk = { (_Float16)acc[fi][fj][0], (_Float16)acc[fi][fj][1],
                             (_Float16)acc[fi][fj][2], (_Float16)acc[fi][fj][3] };
                *(half4*)(VT + ((size_t)(b2 * HH + h2) * DD + d2) * NN + n2) = pk;
            }
        }
}

// ---------------------------------------------------------------------------
// PROJ: C = A * B^T + bias, fp32 out. 128x64 tile, BK=64, XCD bm swizzle.
// ---------------------------------------------------------------------------
__global__ __launch_bounds__(256) void gemmPROJ(
    const _Float16* __restrict__ A, const _Float16* __restrict__ B,
    const float* __restrict__ bias, float* __restrict__ Cout) {
    __shared__ _Float16 sA[128 * 64];
    __shared__ _Float16 sB[64 * 64];
    const int K = CC, N = CC;

    const int t = threadIdx.x;
    const int id = blockIdx.y * gridDim.x + blockIdx.x;
    const int xcd = id & 7, kk = id >> 3;
    const int bm = xcd * 4 + (kk & 3);   // 0..31
    const int bn = kk >> 2;              // 0..15
    const int w = t >> 6, lane = t & 63;
    const int wr = (w >> 1) * 64, wc = (w & 1) * 32;
    const int lr = lane & 15, lg = lane >> 4;

    f32x4 acc[4][2];
#pragma unroll
    for (int a = 0; a < 4; ++a)
#pragma unroll
        for (int b2 = 0; b2 < 2; ++b2)
#pragma unroll
            for (int e = 0; e < 4; ++e) acc[a][b2][e] = 0.f;

    for (int kt = 0; kt < K; kt += 64) {
#pragma unroll
        for (int p = 0; p < 4; ++p) {     // A: 1024 16B-units
            int u = p * 256 + t;
            int rowu = u >> 3, su = (u & 7) ^ (rowu & 7);
            gl_lds16(A + (size_t)(bm * 128 + rowu) * K + kt + su * 8, sA + u * 8);
        }
#pragma unroll
        for (int p = 0; p < 2; ++p) {     // B: 512 16B-units
            int u = p * 256 + t;
            int rowu = u >> 3, su = (u & 7) ^ (rowu & 7);
            gl_lds16(B + (size_t)(bn * 64 + rowu) * K + kt + su * 8, sB + u * 8);
        }
        __syncthreads();

#pragma unroll
        for (int c = 0; c < 2; ++c) {
            half8 af[4], bf[2];
#pragma unroll
            for (int f = 0; f < 4; ++f) {
                int ra = wr + f * 16 + lr;
                af[f] = *(const half8*)((const char*)sA + ((ra * 128 + c * 64 + lg * 16) ^ ((ra & 7) << 4)));
            }
#pragma unroll
            for (int f = 0; f < 2; ++f) {
                int rb = wc + f * 16 + lr;
                bf[f] = *(const half8*)((const char*)sB + ((rb * 128 + c * 64 + lg * 16) ^ ((rb & 7) << 4)));
            }
#pragma unroll
            for (int fi = 0; fi < 4; ++fi)
#pragma unroll
                for (int fj = 0; fj < 2; ++fj)
                    acc[fi][fj] = __builtin_amdgcn_mfma_f32_16x16x32_f16(af[fi], bf[fj], acc[fi][fj], 0, 0, 0);
        }
        __syncthreads();
    }

#pragma unroll
    for (int fi = 0; fi < 4; ++fi)
#pragma unroll
        for (int fj = 0; fj < 2; ++fj)
#pragma unroll
            for (int e = 0; e < 4; ++e) {
                int row = bm * 128 + wr + fi * 16 + lg * 4 + e;
                int col = bn * 64 + wc + fj * 16 + lr;
                Cout[(size_t)row * N + col] = acc[fi][fj][e] + bias[col];
            }
}

// ---------------------------------------------------------------------------
// Producer-consumer fp16 MFMA flash attention with ALiBi — CHAMPION (r10/r12/
// r14, 75.5-76.3us). Measured joint constraint boundary, bracketed 6 ways:
//  - VGPR=64 + default 8-wave/EU heuristic is OPTIMAL: +24 regs spills
//    (+28us, r11); waves_per_eu(2,4) unlock loses gang residency
//    (occupancy 37->21.5%, +12us, r15)
//  - 128 q/block optimal: 64 q/block doubles frag-read redundancy (+4us,
//    r13); 256 q/wave-pair busts the VGPR cliff (r5)
//  - LDS 67KB -> 2 gangs/CU; grid (32,16) keeps K/V L2-pinned per XCD
//    (FETCH 69.7 -> 15.2 MB, r8)
// waves 0-3 = producers (QK^T swapped + lane-local softmax -> P,alpha),
// waves 4-7 = consumers (rescale + PV swapped). One barrier per tile;
// K staged 2 ahead, V 1 ahead, P/alpha double-buffered.
// ---------------------------------------------------------------------------
__global__ __launch_bounds__(512, 4) void attnPC(
    const _Float16* __restrict__ Qh, const _Float16* __restrict__ Kh,
    const _Float16* __restrict__ Vt, _Float16* __restrict__ AO) {
    __shared__ _Float16 sK[2][64 * 64];        // 16 KB
    __shared__ _Float16 sV[2][64 * 64];        // 16 KB
    __shared__ _Float16 sP[2][4][32 * 64];     // 32 KB, per-producer, XOR-swz
    __shared__ float sAl[2][4][32];            // 1 KB  alpha per q
    __shared__ float sL[4][32];                // 0.5 KB l_run publish

    const int t = threadIdx.x, w = t >> 6, lane = t & 63;
    const int lr = lane & 15, lg = lane >> 4;
    const int bh = blockIdx.x, qb = blockIdx.y;   // id%8 = bh%8 -> K/V L2-pinned
    const int b = bh >> 4, h = bh & 15;
    const int i0 = qb * 128;
    const size_t baseND = (size_t)bh * NN * DD;
    const size_t baseDN = (size_t)bh * DD * NN;
    const bool isProd = (w < 4);
    const int pw = w & 3;

    const float slope2 = exp2f(-0.5f * (float)(h + 1)) * 1.44269504f;
    const float s64v = slope2 * 64.f;
    const float s16v = slope2 * 16.f;
    float cini0[4];
#pragma unroll
    for (int e = 0; e < 4; ++e) cini0[e] = slope2 * (float)(lg * 4 + e);

    // 512-thread staging: one 16B unit per thread per call
    auto stageK = [&](int buf, int jt) {
        int rowu = t >> 3, su = (t & 7) ^ (rowu & 7);
        gl_lds16(Kh + baseND + (size_t)(jt * 64 + rowu) * DD + su * 8, &sK[buf][t * 8]);
    };
    auto stageV = [&](int buf, int jt) {
        int rowu = t >> 3, su = (t & 7) ^ (rowu & 7);
        gl_lds16(Vt + baseDN + (size_t)rowu * NN + jt * 64 + su * 8, &sV[buf][t * 8]);
    };

    // ---- producer state ----
    half8 qf[2][2];
    float m_run[2], l_run[2], tbp = 0.f;
    // ---- consumer state ----
    f32x4 accO[2][4];

    if (isProd) {
#pragma unroll
        for (int u = 0; u < 2; ++u) {
            const size_t qoff = baseND + (size_t)(i0 + pw * 32 + u * 16 + lr) * DD;
            qf[u][0] = *(const half8*)(Qh + qoff + 0 * 32 + lg * 8);
            qf[u][1] = *(const half8*)(Qh + qoff + 1 * 32 + lg * 8);
        }
        m_run[0] = m_run[1] = -INFINITY;
        l_run[0] = l_run[1] = 0.f;
    } else {
#pragma unroll
        for (int u = 0; u < 2; ++u)
#pragma unroll
            for (int c2 = 0; c2 < 4; ++c2)
                accO[u][c2][0] = accO[u][c2][1] = accO[u][c2][2] = accO[u][c2][3] = 0.f;
    }

    // producer step: QK^T + softmax + publish for one tile into sP/sAl[pb]
    auto prodStep = [&](int pb, int kb) {
        f32x4 s0[4], s1[4];
#pragma unroll
        for (int ct = 0; ct < 4; ++ct) {
            float base = tbp + s16v * (float)ct;
#pragma unroll
            for (int e = 0; e < 4; ++e) { s0[ct][e] = base + cini0[e]; s1[ct][e] = s0[ct][e]; }
        }
        __builtin_amdgcn_s_setprio(1);
#pragma unroll
        for (int ct = 0; ct < 4; ++ct)
#pragma unroll
            for (int c = 0; c < 2; ++c) {
                int row = ct * 16 + lr;
                half8 kf = *(const half8*)((const char*)&sK[kb][0] +
                    ((row * 128 + c * 64 + lg * 16) ^ ((row & 7) << 4)));
                s0[ct] = __builtin_amdgcn_mfma_f32_16x16x32_f16(kf, qf[0][c], s0[ct], 0, 0, 0);
                s1[ct] = __builtin_amdgcn_mfma_f32_16x16x32_f16(kf, qf[1][c], s1[ct], 0, 0, 0);
            }
        __builtin_amdgcn_s_setprio(0);
#pragma unroll
        for (int u = 0; u < 2; ++u) {
            f32x4* s = u ? s1 : s0;
            float x0 = fmaxf(fmaxf(s[0][0], s[0][1]), fmaxf(s[0][2], s[0][3]));
            float x1 = fmaxf(fmaxf(s[1][0], s[1][1]), fmaxf(s[1][2], s[1][3]));
            float x2 = fmaxf(fmaxf(s[2][0], s[2][1]), fmaxf(s[2][2], s[2][3]));
            float x3 = fmaxf(fmaxf(s[3][0], s[3][1]), fmaxf(s[3][2], s[3][3]));
            float mx = fmaxf(fmaxf(x0, x1), fmaxf(x2, x3));
            mx = fmaxf(mx, __shfl_xor(mx, 16, 64));
            mx = fmaxf(mx, __shfl_xor(mx, 32, 64));
            float mnew = fmaxf(m_run[u], mx);
            float al = exp2_fast(m_run[u] - mnew);   // first tile: exp2(-inf)=0
#pragma unroll
            for (int ct = 0; ct < 4; ++ct)
#pragma unroll
                for (int e = 0; e < 4; ++e) s[ct][e] = exp2_fast(s[ct][e] - mnew);
            float y0 = (s[0][0] + s[0][1]) + (s[0][2] + s[0][3]);
            float y1 = (s[1][0] + s[1][1]) + (s[1][2] + s[1][3]);
            float y2 = (s[2][0] + s[2][1]) + (s[2][2] + s[2][3]);
            float y3 = (s[3][0] + s[3][1]) + (s[3][2] + s[3][3]);
            float sum = (y0 + y1) + (y2 + y3);
            sum += __shfl_xor(sum, 16, 64);
            sum += __shfl_xor(sum, 32, 64);
            m_run[u] = mnew;
            l_run[u] = l_run[u] * al + sum;
            int row = u * 16 + lr;
#pragma unroll
            for (int ct = 0; ct < 4; ++ct) {
                unsigned plo = __builtin_bit_cast(unsigned,
                    __builtin_amdgcn_cvt_pkrtz(s[ct][0], s[ct][1]));
                unsigned phi = __builtin_bit_cast(unsigned,
                    __builtin_amdgcn_cvt_pkrtz(s[ct][2], s[ct][3]));
                uint2 pk = { plo, phi };
                *(uint2*)((char*)sP[pb][pw] + ((row * 128 + ct * 32 + lg * 8) ^ ((lr & 7) << 4))) = pk;
            }
            if (lg == 0) sAl[pb][pw][row] = al;
        }
        tbp += s64v;
    };

    // consumer step: rescale + PV for one tile from sP/sAl/sV[vb]
    auto consStep = [&](int vb) {
        float al0 = sAl[vb][pw][lr];
        float al1 = sAl[vb][pw][16 + lr];
#pragma unroll
        for (int c2 = 0; c2 < 4; ++c2)
#pragma unroll
            for (int e = 0; e < 4; ++e) { accO[0][c2][e] *= al0; accO[1][c2][e] *= al1; }
        half8 pb0[2], pb1[2];
#pragma unroll
        for (int c = 0; c < 2; ++c) {
            pb0[c] = *(const half8*)((const char*)sP[vb][pw] +
                ((lr * 128 + c * 64 + lg * 16) ^ ((lr & 7) << 4)));
            pb1[c] = *(const half8*)((const char*)sP[vb][pw] +
                (((16 + lr) * 128 + c * 64 + lg * 16) ^ ((lr & 7) << 4)));
        }
        __builtin_amdgcn_s_setprio(1);
#pragma unroll
        for (int ctd = 0; ctd < 4; ++ctd)
#pragma unroll
            for (int c = 0; c < 2; ++c) {
                int row = ctd * 16 + lr;
                half8 vf = *(const half8*)((const char*)&sV[vb][0] +
                    ((row * 128 + c * 64 + lg * 16) ^ ((row & 7) << 4)));
                accO[0][ctd] = __builtin_amdgcn_mfma_f32_16x16x32_f16(vf, pb0[c], accO[0][ctd], 0, 0, 0);
                accO[1][ctd] = __builtin_amdgcn_mfma_f32_16x16x32_f16(vf, pb1[c], accO[1][ctd], 0, 0, 0);
            }
        __builtin_amdgcn_s_setprio(0);
    };

    // ---- prologue ----
    stageK(0, 0); stageK(1, 1); stageV(0, 0);
    __syncthreads();                 // K0,K1,V0 ready
    if (isProd) prodStep(0, 0);      // tile 0 -> P[0], alpha[0]
    __syncthreads();                 // P[0] ready

    // ---- main loop: one barrier per tile ----
    for (int j = 0; j < 32; ++j) {
        if (j + 2 < 32) stageK(j & 1, j + 2);          // overwrites K(j): dead
        if (j + 1 < 32) stageV((j + 1) & 1, j + 1);    // overwrites V(j-1): dead
        if (isProd) {
            if (j + 1 < 32) prodStep((j + 1) & 1, (j + 1) & 1);
        } else {
            consStep(j & 1);
        }
        __syncthreads();
    }

    // ---- l_run handoff + epilogue (consumers write AO) ----
    if (isProd && lg == 0) { sL[pw][lr] = l_run[0]; sL[pw][16 + lr] = l_run[1]; }
    __syncthreads();
    if (!isProd) {
#pragma unroll
        for (int u = 0; u < 2; ++u) {
            float rl = 1.0f / sL[pw][u * 16 + lr];
            const size_t obase = ((size_t)b * NN + i0 + pw * 32 + u * 16 + lr) * CC + h * DD;
#pragma unroll
            for (int ctd = 0; ctd < 4; ++ctd) {
                half4 ov = { (_Float16)(accO[u][ctd][0] * rl), (_Float16)(accO[u][ctd][1] * rl),
                             (_Float16)(accO[u][ctd][2] * rl), (_Float16)(accO[u][ctd][3] * rl) };
                *(half4*)(AO + obase + ctd * 16 + lg * 4) = ov;
            }
        }
    }
}

// ---------------------------------------------------------------------------
extern "C" void kernel_launch(void* const* d_in, const int* in_sizes, int n_in,
                              void* d_out, int out_size, void* d_ws, size_t ws_size,
                              hipStream_t stream) {
    const float* x  = (const float*)d_in[0];
    const float* Wq = (const float*)d_in[1];
    const float* Wk = (const float*)d_in[2];
    const float* Wv = (const float*)d_in[3];
    const float* Wp = (const float*)d_in[4];
    const float* bp = (const float*)d_in[5];
    float* out = (float*)d_out;

    char* ws = (char*)d_ws;
    const size_t MB = 1024 * 1024;
    _Float16* X16 = (_Float16*)(ws + 0 * MB);    // 8 MB
    _Float16* W16 = (_Float16*)(ws + 8 * MB);    // 4 x 2 MB (Wq,Wk,Wv,Wp)
    _Float16* QH  = (_Float16*)(ws + 16 * MB);   // 8 MB  [B,H,N,D], q*8*log2e
    _Float16* KH  = (_Float16*)(ws + 24 * MB);   // 8 MB  [B,H,N,D]
    _Float16* VT  = (_Float16*)(ws + 32 * MB);   // 8 MB  [B,H,D,N]
    _Float16* AO  = (_Float16*)(ws + 40 * MB);   // 8 MB  [B,N,C]
    _Float16* WP16 = W16 + 3 * 1024 * 1024;

    cvtAll<<<8192, 256, 0, stream>>>(x, Wq, Wk, Wv, Wp, X16, W16);

    const float QSCALE = 8.0f * 1.44269504f;   // fold 1/SCALE and log2(e)
    gemmQKV<<<dim3(3 * CC / 128, MM / 128), 256, 0, stream>>>(X16, W16, QH, KH, VT, QSCALE);

    // grid = (bh, qb): id%8 = bh%8 -> all q-blocks of a head share an XCD
    attnPC<<<dim3(BB * HH, NN / 128), 512, 0, stream>>>(QH, KH, VT, AO);

    gemmPROJ<<<dim3(CC / 64, MM / 128), 256, 0, stream>>>(AO, WP16, bp, out);
}